// Round 1
// baseline (1652.115 us; speedup 1.0000x reference)
//
#include <hip/hip_runtime.h>

#define N_NODES 50000
#define N_EDGES 800000
#define DIM 128
#define NUM_REL 200
#define NREL2 (2 * NUM_REL)
#define NODES_PER_BLK 16

// ---------------------------------------------------------------------------
// Kernel A: merged relation table R[400][128] (W_O path for t<200, W_I else)
//           and rel_new output (rel_emb @ W_R^T + b_R).
// One block per relation row, 128 threads (thread j = output dim j).
// ---------------------------------------------------------------------------
__global__ void rel_tables_kernel(const float* __restrict__ rel_emb,
                                  const float* __restrict__ W_O_w,
                                  const float* __restrict__ W_O_b,
                                  const float* __restrict__ W_I_w,
                                  const float* __restrict__ W_I_b,
                                  const float* __restrict__ W_R_w,
                                  const float* __restrict__ W_R_b,
                                  float* __restrict__ R,
                                  float* __restrict__ rel_new) {
    __shared__ float row[DIM];
    const int t = blockIdx.x;   // 0..399
    const int j = threadIdx.x;  // 0..127
    row[j] = rel_emb[t * DIM + j];
    __syncthreads();

    const bool fwd = (t < NUM_REL);
    // W_O_w / W_I_w are [128][256] row-major; rel part is cols 0..127.
    const float* __restrict__ wSel = (fwd ? W_O_w : W_I_w) + j * (2 * DIM);
    const float* __restrict__ wR = W_R_w + j * DIM;

    float aSel = 0.f, aR = 0.f;
#pragma unroll 8
    for (int k = 0; k < DIM; ++k) {
        const float e = row[k];
        aSel += e * wSel[k];
        aR += e * wR[k];
    }
    R[t * DIM + j] = aSel + (fwd ? W_O_b[j] : W_I_b[j]);
    rel_new[t * DIM + j] = aR + W_R_b[j];
}

// ---------------------------------------------------------------------------
// Kernel B: per-node tables. For each node n:
//   E_O[n] = ent_emb[n] @ (ent-half of W_O)^T
//   E_I[n] = ent_emb[n] @ (ent-half of W_I)^T
//   ent_S[n] = ent_emb[n] @ W_S^T + b_S
// Tiled: 16 nodes per block so each weight element is loaded once per 16
// node-rows (weights stay L1-resident: 3 * 8KB of active lines).
// ---------------------------------------------------------------------------
__global__ void __launch_bounds__(128)
node_tables_kernel(const float* __restrict__ ent_emb,
                   const float* __restrict__ W_O_w,
                   const float* __restrict__ W_I_w,
                   const float* __restrict__ W_S_w,
                   const float* __restrict__ W_S_b,
                   float* __restrict__ E_O,
                   float* __restrict__ E_I,
                   float* __restrict__ ent_S) {
    __shared__ float rows[NODES_PER_BLK][DIM];
    const int n0 = blockIdx.x * NODES_PER_BLK;
    const int j = threadIdx.x;  // output dim

    for (int m = 0; m < NODES_PER_BLK; ++m) {
        const int n = n0 + m;
        rows[m][j] = (n < N_NODES) ? ent_emb[(size_t)n * DIM + j] : 0.f;
    }
    __syncthreads();

    float accO[NODES_PER_BLK];
    float accI[NODES_PER_BLK];
    float accS[NODES_PER_BLK];
#pragma unroll
    for (int m = 0; m < NODES_PER_BLK; ++m) { accO[m] = 0.f; accI[m] = 0.f; accS[m] = 0.f; }

    // ent-half of W_O / W_I = cols 128..255 of the [128][256] matrices.
    const float* __restrict__ wO = W_O_w + j * (2 * DIM) + DIM;
    const float* __restrict__ wI = W_I_w + j * (2 * DIM) + DIM;
    const float* __restrict__ wS = W_S_w + j * DIM;

    for (int k = 0; k < DIM; ++k) {
        const float o = wO[k];
        const float i_ = wI[k];
        const float s = wS[k];
#pragma unroll
        for (int m = 0; m < NODES_PER_BLK; ++m) {
            const float e = rows[m][k];  // LDS broadcast (same addr all lanes)
            accO[m] += e * o;
            accI[m] += e * i_;
            accS[m] += e * s;
        }
    }

    const float bS = W_S_b[j];
    for (int m = 0; m < NODES_PER_BLK; ++m) {
        const int n = n0 + m;
        if (n < N_NODES) {
            E_O[(size_t)n * DIM + j] = accO[m];
            E_I[(size_t)n * DIM + j] = accI[m];
            ent_S[(size_t)n * DIM + j] = accS[m] + bS;
        }
    }
}

// ---------------------------------------------------------------------------
// Kernel C: per-edge gather + atomic scatter-add.
// msg = R[etype] + (etype<200 ? E_O : E_I)[src]; agg[dst] += msg; deg[dst]++.
// 32 lanes per edge, float4 per lane (512B contiguous per edge).
// ---------------------------------------------------------------------------
__global__ void __launch_bounds__(256)
edge_scatter_kernel(const int* __restrict__ src,
                    const int* __restrict__ dst,
                    const int* __restrict__ et,
                    const float* __restrict__ R,
                    const float* __restrict__ E_O,
                    const float* __restrict__ E_I,
                    float* __restrict__ agg,
                    float* __restrict__ deg) {
    const int e = blockIdx.x * 8 + (threadIdx.x >> 5);
    if (e >= N_EDGES) return;
    const int l = threadIdx.x & 31;

    const int s = src[e];
    const int d = dst[e];
    const int t = et[e];

    const float* __restrict__ E = (t < NUM_REL) ? E_O : E_I;

    const float4 r = *(const float4*)(R + (size_t)t * DIM + l * 4);
    const float4 x = *(const float4*)(E + (size_t)s * DIM + l * 4);

    float* a = agg + (size_t)d * DIM + l * 4;
    atomicAdd(a + 0, r.x + x.x);
    atomicAdd(a + 1, r.y + x.y);
    atomicAdd(a + 2, r.z + x.z);
    atomicAdd(a + 3, r.w + x.w);
    if (l == 0) atomicAdd(deg + d, 1.0f);
}

// ---------------------------------------------------------------------------
// Kernel D: finalize. out_ent = ent_S + agg / max(deg, 1).
// float4 grid-stride-free elementwise.
// ---------------------------------------------------------------------------
__global__ void __launch_bounds__(256)
finalize_kernel(const float* __restrict__ ent_S,
                const float* __restrict__ agg,
                const float* __restrict__ deg,
                float* __restrict__ out_ent) {
    const int idx = blockIdx.x * blockDim.x + threadIdx.x;  // over N_NODES*32
    if (idx >= N_NODES * (DIM / 4)) return;
    const int n = idx >> 5;  // DIM/4 = 32 float4 per node
    const float dg = deg[n];
    const float inv = 1.0f / fmaxf(dg, 1.0f);
    const float4 a = ((const float4*)agg)[idx];
    const float4 s = ((const float4*)ent_S)[idx];
    float4 o;
    o.x = s.x + a.x * inv;
    o.y = s.y + a.y * inv;
    o.z = s.z + a.z * inv;
    o.w = s.w + a.w * inv;
    ((float4*)out_ent)[idx] = o;
}

extern "C" void kernel_launch(void* const* d_in, const int* in_sizes, int n_in,
                              void* d_out, int out_size, void* d_ws, size_t ws_size,
                              hipStream_t stream) {
    const int* src = (const int*)d_in[0];
    const int* dst = (const int*)d_in[1];
    const int* et = (const int*)d_in[2];
    const float* ent_emb = (const float*)d_in[3];
    const float* rel_emb = (const float*)d_in[4];
    const float* W_O_w = (const float*)d_in[5];
    const float* W_O_b = (const float*)d_in[6];
    const float* W_I_w = (const float*)d_in[7];
    const float* W_I_b = (const float*)d_in[8];
    const float* W_S_w = (const float*)d_in[9];
    const float* W_S_b = (const float*)d_in[10];
    const float* W_R_w = (const float*)d_in[11];
    const float* W_R_b = (const float*)d_in[12];

    float* out_ent = (float*)d_out;                      // [50000*128]
    float* out_rel = out_ent + (size_t)N_NODES * DIM;    // [400*128]

    // Workspace layout (floats): R | E_O | E_I | ent_S | agg | deg
    float* ws = (float*)d_ws;
    float* R = ws;
    ws += (size_t)NREL2 * DIM;  // 51,200
    float* E_O = ws;
    ws += (size_t)N_NODES * DIM;  // 6.4M
    float* E_I = ws;
    ws += (size_t)N_NODES * DIM;
    float* ent_S = ws;
    ws += (size_t)N_NODES * DIM;
    float* agg = ws;
    ws += (size_t)N_NODES * DIM;
    float* deg = ws;
    ws += N_NODES;
    // total ~102.8 MB

    // Zero the accumulators (graph-capture-safe).
    hipMemsetAsync(agg, 0, (size_t)N_NODES * DIM * sizeof(float), stream);
    hipMemsetAsync(deg, 0, (size_t)N_NODES * sizeof(float), stream);

    rel_tables_kernel<<<NREL2, DIM, 0, stream>>>(rel_emb, W_O_w, W_O_b, W_I_w, W_I_b,
                                                 W_R_w, W_R_b, R, out_rel);

    node_tables_kernel<<<(N_NODES + NODES_PER_BLK - 1) / NODES_PER_BLK, DIM, 0, stream>>>(
        ent_emb, W_O_w, W_I_w, W_S_w, W_S_b, E_O, E_I, ent_S);

    edge_scatter_kernel<<<(N_EDGES + 7) / 8, 256, 0, stream>>>(src, dst, et, R, E_O, E_I,
                                                               agg, deg);

    finalize_kernel<<<(N_NODES * (DIM / 4) + 255) / 256, 256, 0, stream>>>(ent_S, agg, deg,
                                                                           out_ent);
}

// Round 2
// 400.651 us; speedup vs baseline: 4.1236x; 4.1236x over previous
//
#include <hip/hip_runtime.h>

#define N_NODES 50000
#define N_EDGES 800000
#define DIM 128
#define NUM_REL 200
#define NREL2 (2 * NUM_REL)
#define NODES_PER_BLK 16
#define SCAN_BLK 512
#define SCAN_NBLK ((N_NODES + SCAN_BLK - 1) / SCAN_BLK)  // 98

// ---------------------------------------------------------------------------
// Kernel A: merged relation table R[400][128] (W_O rel-half for t<200, W_I
// rel-half else, + matching bias) and rel_new output (rel_emb @ W_R^T + b_R).
// ---------------------------------------------------------------------------
__global__ void rel_tables_kernel(const float* __restrict__ rel_emb,
                                  const float* __restrict__ W_O_w,
                                  const float* __restrict__ W_O_b,
                                  const float* __restrict__ W_I_w,
                                  const float* __restrict__ W_I_b,
                                  const float* __restrict__ W_R_w,
                                  const float* __restrict__ W_R_b,
                                  float* __restrict__ R,
                                  float* __restrict__ rel_new) {
    __shared__ float row[DIM];
    const int t = blockIdx.x;   // 0..399
    const int j = threadIdx.x;  // 0..127
    row[j] = rel_emb[t * DIM + j];
    __syncthreads();

    const bool fwd = (t < NUM_REL);
    const float* __restrict__ wSel = (fwd ? W_O_w : W_I_w) + j * (2 * DIM);
    const float* __restrict__ wR = W_R_w + j * DIM;

    float aSel = 0.f, aR = 0.f;
#pragma unroll 8
    for (int k = 0; k < DIM; ++k) {
        const float e = row[k];
        aSel += e * wSel[k];
        aR += e * wR[k];
    }
    R[t * DIM + j] = aSel + (fwd ? W_O_b[j] : W_I_b[j]);
    rel_new[t * DIM + j] = aR + W_R_b[j];
}

// ---------------------------------------------------------------------------
// Kernel B: per-node tables into one contiguous EE buffer:
//   EE[n]          = ent_emb[n] @ (ent-half of W_O)^T      (rows 0..49999)
//   EE[50000+n]    = ent_emb[n] @ (ent-half of W_I)^T
//   ent_S[n]       = ent_emb[n] @ W_S^T + b_S
// ---------------------------------------------------------------------------
__global__ void __launch_bounds__(128)
node_tables_kernel(const float* __restrict__ ent_emb,
                   const float* __restrict__ W_O_w,
                   const float* __restrict__ W_I_w,
                   const float* __restrict__ W_S_w,
                   const float* __restrict__ W_S_b,
                   float* __restrict__ EE,
                   float* __restrict__ ent_S) {
    __shared__ float rows[NODES_PER_BLK][DIM];
    const int n0 = blockIdx.x * NODES_PER_BLK;
    const int j = threadIdx.x;

    for (int m = 0; m < NODES_PER_BLK; ++m) {
        const int n = n0 + m;
        rows[m][j] = (n < N_NODES) ? ent_emb[(size_t)n * DIM + j] : 0.f;
    }
    __syncthreads();

    float accO[NODES_PER_BLK], accI[NODES_PER_BLK], accS[NODES_PER_BLK];
#pragma unroll
    for (int m = 0; m < NODES_PER_BLK; ++m) { accO[m] = 0.f; accI[m] = 0.f; accS[m] = 0.f; }

    const float* __restrict__ wO = W_O_w + j * (2 * DIM) + DIM;
    const float* __restrict__ wI = W_I_w + j * (2 * DIM) + DIM;
    const float* __restrict__ wS = W_S_w + j * DIM;

    for (int k = 0; k < DIM; ++k) {
        const float o = wO[k];
        const float i_ = wI[k];
        const float s = wS[k];
#pragma unroll
        for (int m = 0; m < NODES_PER_BLK; ++m) {
            const float e = rows[m][k];
            accO[m] += e * o;
            accI[m] += e * i_;
            accS[m] += e * s;
        }
    }

    const float bS = W_S_b[j];
    for (int m = 0; m < NODES_PER_BLK; ++m) {
        const int n = n0 + m;
        if (n < N_NODES) {
            EE[(size_t)n * DIM + j] = accO[m];
            EE[((size_t)N_NODES + n) * DIM + j] = accI[m];
            ent_S[(size_t)n * DIM + j] = accS[m] + bS;
        }
    }
}

// ---------------------------------------------------------------------------
// CSR construction: histogram -> 3-phase exclusive scan -> fill.
// ---------------------------------------------------------------------------
__global__ void __launch_bounds__(256)
hist_kernel(const int* __restrict__ dst, int* __restrict__ counts) {
    const int e = blockIdx.x * 256 + threadIdx.x;
    if (e < N_EDGES) atomicAdd(&counts[dst[e]], 1);
}

__global__ void __launch_bounds__(SCAN_BLK)
scan1_kernel(const int* __restrict__ counts, int* __restrict__ offs,
             int* __restrict__ bsum) {
    __shared__ int tmp[SCAN_BLK];
    const int i = blockIdx.x * SCAN_BLK + threadIdx.x;
    const int v = (i < N_NODES) ? counts[i] : 0;
    tmp[threadIdx.x] = v;
    __syncthreads();
    for (int off = 1; off < SCAN_BLK; off <<= 1) {
        const int t = (threadIdx.x >= off) ? tmp[threadIdx.x - off] : 0;
        __syncthreads();
        tmp[threadIdx.x] += t;
        __syncthreads();
    }
    if (i < N_NODES) offs[i] = tmp[threadIdx.x] - v;  // exclusive
    if (threadIdx.x == SCAN_BLK - 1) bsum[blockIdx.x] = tmp[SCAN_BLK - 1];
}

__global__ void scan2_kernel(int* __restrict__ bsum) {
    if (threadIdx.x == 0 && blockIdx.x == 0) {
        int a = 0;
        for (int i = 0; i < SCAN_NBLK; ++i) {
            const int t = bsum[i];
            bsum[i] = a;
            a += t;
        }
    }
}

__global__ void __launch_bounds__(SCAN_BLK)
scan3_kernel(int* __restrict__ offs, const int* __restrict__ bsum) {
    const int i = blockIdx.x * SCAN_BLK + threadIdx.x;
    if (i < N_NODES) offs[i] += bsum[blockIdx.x];
}

// Fill: sorted-by-dst packed edge payload: row(17b) | etype<<17 (9b).
__global__ void __launch_bounds__(256)
fill_kernel(const int* __restrict__ src, const int* __restrict__ dst,
            const int* __restrict__ et, const int* __restrict__ offs,
            int* __restrict__ cursor, int* __restrict__ sp) {
    const int e = blockIdx.x * 256 + threadIdx.x;
    if (e >= N_EDGES) return;
    const int d = dst[e];
    const int t = et[e];
    const int row = src[e] + ((t < NUM_REL) ? 0 : N_NODES);
    const int pos = atomicAdd(&cursor[d], 1);
    sp[offs[d] + pos] = row | (t << 17);
}

// ---------------------------------------------------------------------------
// Gather-reduce: one wave per node. Lane l owns output floats [2l, 2l+1].
// Edge payloads loaded coalesced (lane-parallel) and broadcast via shfl.
// Fuses finalize: out = ent_S + acc / max(deg,1).
// ---------------------------------------------------------------------------
__global__ void __launch_bounds__(256)
gather_kernel(const int* __restrict__ offs, const int* __restrict__ counts,
              const int* __restrict__ sp, const float* __restrict__ EE,
              const float* __restrict__ R, const float* __restrict__ ent_S,
              float* __restrict__ out_ent) {
    const int node = blockIdx.x * 4 + (threadIdx.x >> 6);
    if (node >= N_NODES) return;
    const int l = threadIdx.x & 63;

    const int beg = offs[node];
    const int cnt = counts[node];

    float ax = 0.f, ay = 0.f;
    for (int base = 0; base < cnt; base += 64) {
        const int kk = min(64, cnt - base);
        const int myp = (base + l < cnt) ? sp[beg + base + l] : 0;
#pragma unroll 4
        for (int i = 0; i < kk; ++i) {
            const int p = __shfl(myp, i);
            const int row = p & 0x1FFFF;
            const int t = p >> 17;
            const float2 e = *(const float2*)(EE + (size_t)row * DIM + 2 * l);
            const float2 r = *(const float2*)(R + (size_t)t * DIM + 2 * l);
            ax += e.x + r.x;
            ay += e.y + r.y;
        }
    }

    const float inv = 1.0f / fmaxf((float)cnt, 1.0f);
    const float2 s = *(const float2*)(ent_S + (size_t)node * DIM + 2 * l);
    float2 o;
    o.x = s.x + ax * inv;
    o.y = s.y + ay * inv;
    *(float2*)(out_ent + (size_t)node * DIM + 2 * l) = o;
}

extern "C" void kernel_launch(void* const* d_in, const int* in_sizes, int n_in,
                              void* d_out, int out_size, void* d_ws, size_t ws_size,
                              hipStream_t stream) {
    const int* src = (const int*)d_in[0];
    const int* dst = (const int*)d_in[1];
    const int* et = (const int*)d_in[2];
    const float* ent_emb = (const float*)d_in[3];
    const float* rel_emb = (const float*)d_in[4];
    const float* W_O_w = (const float*)d_in[5];
    const float* W_O_b = (const float*)d_in[6];
    const float* W_I_w = (const float*)d_in[7];
    const float* W_I_b = (const float*)d_in[8];
    const float* W_S_w = (const float*)d_in[9];
    const float* W_S_b = (const float*)d_in[10];
    const float* W_R_w = (const float*)d_in[11];
    const float* W_R_b = (const float*)d_in[12];

    float* out_ent = (float*)d_out;                    // [50000*128]
    float* out_rel = out_ent + (size_t)N_NODES * DIM;  // [400*128]

    // Workspace layout: R | EE | ent_S | counts,cursor | bsum | offs | sp
    float* wsf = (float*)d_ws;
    float* R = wsf;
    wsf += (size_t)NREL2 * DIM;          // 51,200 f
    float* EE = wsf;
    wsf += (size_t)2 * N_NODES * DIM;    // 12.8M f
    float* ent_S = wsf;
    wsf += (size_t)N_NODES * DIM;        // 6.4M f
    int* counts = (int*)wsf;
    int* cursor = counts + N_NODES;
    int* bsum = cursor + N_NODES;
    int* offs = bsum + 128;
    int* sp = offs + N_NODES;
    // total ~80.8 MB

    // Zero counts + cursor in one shot (adjacent).
    hipMemsetAsync(counts, 0, 2 * N_NODES * sizeof(int), stream);

    rel_tables_kernel<<<NREL2, DIM, 0, stream>>>(rel_emb, W_O_w, W_O_b, W_I_w, W_I_b,
                                                 W_R_w, W_R_b, R, out_rel);

    node_tables_kernel<<<(N_NODES + NODES_PER_BLK - 1) / NODES_PER_BLK, DIM, 0, stream>>>(
        ent_emb, W_O_w, W_I_w, W_S_w, W_S_b, EE, ent_S);

    hist_kernel<<<(N_EDGES + 255) / 256, 256, 0, stream>>>(dst, counts);
    scan1_kernel<<<SCAN_NBLK, SCAN_BLK, 0, stream>>>(counts, offs, bsum);
    scan2_kernel<<<1, 64, 0, stream>>>(bsum);
    scan3_kernel<<<SCAN_NBLK, SCAN_BLK, 0, stream>>>(offs, bsum);
    fill_kernel<<<(N_EDGES + 255) / 256, 256, 0, stream>>>(src, dst, et, offs, cursor, sp);

    gather_kernel<<<(N_NODES + 3) / 4, 256, 0, stream>>>(offs, counts, sp, EE, R, ent_S,
                                                         out_ent);
}

// Round 3
// 293.140 us; speedup vs baseline: 5.6359x; 1.3668x over previous
//
#include <hip/hip_runtime.h>

#define N_NODES 50000
#define N_EDGES 800000
#define DIM 128
#define NUM_REL 200
#define NREL2 (2 * NUM_REL)
#define SCAN_BLK 512
#define SCAN_NBLK ((N_NODES + SCAN_BLK - 1) / SCAN_BLK)  // 98

// ---------------------------------------------------------------------------
// Kernel A: merged relation table R[400][128] (W_O rel-half for t<200, W_I
// rel-half else, + matching bias) and rel_new output (rel_emb @ W_R^T + b_R).
// ---------------------------------------------------------------------------
__global__ void rel_tables_kernel(const float* __restrict__ rel_emb,
                                  const float* __restrict__ W_O_w,
                                  const float* __restrict__ W_O_b,
                                  const float* __restrict__ W_I_w,
                                  const float* __restrict__ W_I_b,
                                  const float* __restrict__ W_R_w,
                                  const float* __restrict__ W_R_b,
                                  float* __restrict__ R,
                                  float* __restrict__ rel_new) {
    __shared__ float row[DIM];
    const int t = blockIdx.x;   // 0..399
    const int j = threadIdx.x;  // 0..127
    row[j] = rel_emb[t * DIM + j];
    __syncthreads();

    const bool fwd = (t < NUM_REL);
    const float* __restrict__ wSel = (fwd ? W_O_w : W_I_w) + j * (2 * DIM);
    const float* __restrict__ wR = W_R_w + j * DIM;

    float aSel = 0.f, aR = 0.f;
#pragma unroll 8
    for (int k = 0; k < DIM; ++k) {
        const float e = row[k];
        aSel += e * wSel[k];
        aR += e * wR[k];
    }
    R[t * DIM + j] = aSel + (fwd ? W_O_b[j] : W_I_b[j]);
    rel_new[t * DIM + j] = aR + W_R_b[j];
}

// ---------------------------------------------------------------------------
// Kernel B (REWRITTEN): per-node tables, 32 nodes/block, 256 threads.
//   EE[n]       = ent_emb[n] @ (ent-half of W_O)^T    (rows 0..49999)
//   EE[50000+n] = ent_emb[n] @ (ent-half of W_I)^T
//   ent_S[n]    = ent_emb[n] @ W_S^T + b_S
// Named scalar accumulators (macro-expanded) guarantee register residency —
// the previous array version spilled to scratch (VGPR_Count=36 < 48 live
// accumulators, VALUBusy 21%).
// thread = (g, j): g = upper/lower 16-node half, j = output column.
// ---------------------------------------------------------------------------
#define REP16(F) F(0) F(1) F(2) F(3) F(4) F(5) F(6) F(7) \
                 F(8) F(9) F(10) F(11) F(12) F(13) F(14) F(15)

__global__ void __launch_bounds__(256)
node_tables_kernel(const float* __restrict__ ent_emb,
                   const float* __restrict__ W_O_w,
                   const float* __restrict__ W_I_w,
                   const float* __restrict__ W_S_w,
                   const float* __restrict__ W_S_b,
                   float* __restrict__ EE,
                   float* __restrict__ ent_S) {
    __shared__ float rows[32][DIM];  // 16 KB
    const int t = threadIdx.x;
    const int g = t >> 7;    // 0..1  (node half-tile)
    const int j = t & 127;   // output column
    const int n0 = blockIdx.x * 32;

    // Stage 32 node rows (4096 floats) with 1024 float4 ops, coalesced.
    float* L = &rows[0][0];
#pragma unroll
    for (int i = 0; i < 4; ++i) {
        const int fi = i * 256 + t;        // float4 index
        const int n = n0 + (fi >> 5);      // 32 float4 per row
        float4 v = make_float4(0.f, 0.f, 0.f, 0.f);
        if (n < N_NODES) v = *(const float4*)(ent_emb + (size_t)n * DIM + (fi & 31) * 4);
        *(float4*)(L + fi * 4) = v;
    }
    __syncthreads();

#define DECL(m) float aO_##m = 0.f, aI_##m = 0.f, aS_##m = 0.f;
    REP16(DECL)
#undef DECL

    const float* __restrict__ wO = W_O_w + j * (2 * DIM) + DIM;  // ent-half
    const float* __restrict__ wI = W_I_w + j * (2 * DIM) + DIM;
    const float* __restrict__ wS = W_S_w + j * DIM;
    const float* Lg = L + (g << 4) * DIM;  // this half-tile's 16 rows

#pragma unroll 2
    for (int k4 = 0; k4 < DIM / 4; ++k4) {
        const float4 o = *(const float4*)(wO + k4 * 4);
        const float4 ii = *(const float4*)(wI + k4 * 4);
        const float4 s = *(const float4*)(wS + k4 * 4);
#define STEP(m)                                                               \
        {                                                                     \
            const float4 e = *(const float4*)(Lg + (m) * DIM + k4 * 4);       \
            aO_##m += e.x * o.x + e.y * o.y + e.z * o.z + e.w * o.w;          \
            aI_##m += e.x * ii.x + e.y * ii.y + e.z * ii.z + e.w * ii.w;      \
            aS_##m += e.x * s.x + e.y * s.y + e.z * s.z + e.w * s.w;          \
        }
        REP16(STEP)
#undef STEP
    }

    const float bS = W_S_b[j];
#define STORE(m)                                                              \
    {                                                                         \
        const int n = n0 + (g << 4) + (m);                                    \
        if (n < N_NODES) {                                                    \
            EE[(size_t)n * DIM + j] = aO_##m;                                 \
            EE[((size_t)N_NODES + n) * DIM + j] = aI_##m;                     \
            ent_S[(size_t)n * DIM + j] = aS_##m + bS;                         \
        }                                                                     \
    }
    REP16(STORE)
#undef STORE
}

// ---------------------------------------------------------------------------
// CSR construction: histogram -> 3-phase exclusive scan -> fill.
// ---------------------------------------------------------------------------
__global__ void __launch_bounds__(256)
hist_kernel(const int* __restrict__ dst, int* __restrict__ counts) {
    const int e = blockIdx.x * 256 + threadIdx.x;
    if (e < N_EDGES) atomicAdd(&counts[dst[e]], 1);
}

__global__ void __launch_bounds__(SCAN_BLK)
scan1_kernel(const int* __restrict__ counts, int* __restrict__ offs,
             int* __restrict__ bsum) {
    __shared__ int tmp[SCAN_BLK];
    const int i = blockIdx.x * SCAN_BLK + threadIdx.x;
    const int v = (i < N_NODES) ? counts[i] : 0;
    tmp[threadIdx.x] = v;
    __syncthreads();
    for (int off = 1; off < SCAN_BLK; off <<= 1) {
        const int t = (threadIdx.x >= off) ? tmp[threadIdx.x - off] : 0;
        __syncthreads();
        tmp[threadIdx.x] += t;
        __syncthreads();
    }
    if (i < N_NODES) offs[i] = tmp[threadIdx.x] - v;  // exclusive
    if (threadIdx.x == SCAN_BLK - 1) bsum[blockIdx.x] = tmp[SCAN_BLK - 1];
}

__global__ void scan2_kernel(int* __restrict__ bsum) {
    if (threadIdx.x == 0 && blockIdx.x == 0) {
        int a = 0;
        for (int i = 0; i < SCAN_NBLK; ++i) {
            const int t = bsum[i];
            bsum[i] = a;
            a += t;
        }
    }
}

__global__ void __launch_bounds__(SCAN_BLK)
scan3_kernel(int* __restrict__ offs, const int* __restrict__ bsum) {
    const int i = blockIdx.x * SCAN_BLK + threadIdx.x;
    if (i < N_NODES) offs[i] += bsum[blockIdx.x];
}

// Fill: sorted-by-dst packed edge payload: row(17b) | etype<<17 (9b).
__global__ void __launch_bounds__(256)
fill_kernel(const int* __restrict__ src, const int* __restrict__ dst,
            const int* __restrict__ et, const int* __restrict__ offs,
            int* __restrict__ cursor, int* __restrict__ sp) {
    const int e = blockIdx.x * 256 + threadIdx.x;
    if (e >= N_EDGES) return;
    const int d = dst[e];
    const int t = et[e];
    const int row = src[e] + ((t < NUM_REL) ? 0 : N_NODES);
    const int pos = atomicAdd(&cursor[d], 1);
    sp[offs[d] + pos] = row | (t << 17);
}

// ---------------------------------------------------------------------------
// Gather-reduce: one wave per node. Lane l owns output floats [2l, 2l+1].
// Fuses finalize: out = ent_S + acc / max(deg,1).
// ---------------------------------------------------------------------------
__global__ void __launch_bounds__(256)
gather_kernel(const int* __restrict__ offs, const int* __restrict__ counts,
              const int* __restrict__ sp, const float* __restrict__ EE,
              const float* __restrict__ R, const float* __restrict__ ent_S,
              float* __restrict__ out_ent) {
    const int node = blockIdx.x * 4 + (threadIdx.x >> 6);
    if (node >= N_NODES) return;
    const int l = threadIdx.x & 63;

    const int beg = offs[node];
    const int cnt = counts[node];

    float ax = 0.f, ay = 0.f;
    for (int base = 0; base < cnt; base += 64) {
        const int kk = min(64, cnt - base);
        const int myp = (base + l < cnt) ? sp[beg + base + l] : 0;
#pragma unroll 4
        for (int i = 0; i < kk; ++i) {
            const int p = __shfl(myp, i);
            const int row = p & 0x1FFFF;
            const int t = p >> 17;
            const float2 e = *(const float2*)(EE + (size_t)row * DIM + 2 * l);
            const float2 r = *(const float2*)(R + (size_t)t * DIM + 2 * l);
            ax += e.x + r.x;
            ay += e.y + r.y;
        }
    }

    const float inv = 1.0f / fmaxf((float)cnt, 1.0f);
    const float2 s = *(const float2*)(ent_S + (size_t)node * DIM + 2 * l);
    float2 o;
    o.x = s.x + ax * inv;
    o.y = s.y + ay * inv;
    *(float2*)(out_ent + (size_t)node * DIM + 2 * l) = o;
}

extern "C" void kernel_launch(void* const* d_in, const int* in_sizes, int n_in,
                              void* d_out, int out_size, void* d_ws, size_t ws_size,
                              hipStream_t stream) {
    const int* src = (const int*)d_in[0];
    const int* dst = (const int*)d_in[1];
    const int* et = (const int*)d_in[2];
    const float* ent_emb = (const float*)d_in[3];
    const float* rel_emb = (const float*)d_in[4];
    const float* W_O_w = (const float*)d_in[5];
    const float* W_O_b = (const float*)d_in[6];
    const float* W_I_w = (const float*)d_in[7];
    const float* W_I_b = (const float*)d_in[8];
    const float* W_S_w = (const float*)d_in[9];
    const float* W_S_b = (const float*)d_in[10];
    const float* W_R_w = (const float*)d_in[11];
    const float* W_R_b = (const float*)d_in[12];

    float* out_ent = (float*)d_out;                    // [50000*128]
    float* out_rel = out_ent + (size_t)N_NODES * DIM;  // [400*128]

    // Workspace layout: R | EE | ent_S | counts,cursor | bsum | offs | sp
    float* wsf = (float*)d_ws;
    float* R = wsf;
    wsf += (size_t)NREL2 * DIM;          // 51,200 f
    float* EE = wsf;
    wsf += (size_t)2 * N_NODES * DIM;    // 12.8M f
    float* ent_S = wsf;
    wsf += (size_t)N_NODES * DIM;        // 6.4M f
    int* counts = (int*)wsf;
    int* cursor = counts + N_NODES;
    int* bsum = cursor + N_NODES;
    int* offs = bsum + 128;
    int* sp = offs + N_NODES;
    // total ~80.8 MB

    hipMemsetAsync(counts, 0, 2 * N_NODES * sizeof(int), stream);

    rel_tables_kernel<<<NREL2, DIM, 0, stream>>>(rel_emb, W_O_w, W_O_b, W_I_w, W_I_b,
                                                 W_R_w, W_R_b, R, out_rel);

    node_tables_kernel<<<(N_NODES + 31) / 32, 256, 0, stream>>>(
        ent_emb, W_O_w, W_I_w, W_S_w, W_S_b, EE, ent_S);

    hist_kernel<<<(N_EDGES + 255) / 256, 256, 0, stream>>>(dst, counts);
    scan1_kernel<<<SCAN_NBLK, SCAN_BLK, 0, stream>>>(counts, offs, bsum);
    scan2_kernel<<<1, 64, 0, stream>>>(bsum);
    scan3_kernel<<<SCAN_NBLK, SCAN_BLK, 0, stream>>>(offs, bsum);
    fill_kernel<<<(N_EDGES + 255) / 256, 256, 0, stream>>>(src, dst, et, offs, cursor, sp);

    gather_kernel<<<(N_NODES + 3) / 4, 256, 0, stream>>>(offs, counts, sp, EE, R, ent_S,
                                                         out_ent);
}